// Round 3
// baseline (18977.199 us; speedup 1.0000x reference)
//
#include <hip/hip_runtime.h>
#include <hip/hip_bf16.h>
#include <math.h>

typedef __hip_bfloat16 bf16;

// Problem constants
constexpr int cB = 16, cL = 2048, cWIN = 128, cD = 512, cH = 8, cFF = 2048;
constexpr int cNL = 3, cV = 32000, cM = 32;
constexpr int cHD = cD / cH;     // 64
constexpr int cS = cWIN + 1;     // 129
constexpr float cEPS = 1e-5f;
constexpr float cRECON_W = 0.1f;

__device__ __forceinline__ float b2f(bf16 x) { return __bfloat162float(x); }

// dtype-agnostic load with ELEMENT offset: f32 flag selects interpretation.
__device__ __forceinline__ float ldx(const void* p, size_t i, int f32) {
    return f32 ? ((const float*)p)[i]
               : __bfloat162float(((const bf16*)p)[i]);
}

// ---------------------------------------------------------------------------
// dtype detection: x0 ~ N(0,1). bf16 data: all halfwords decode |v|<128.
// float32 data: even halfwords are low mantissa bits -> ~47% decode |v|>=128.
__global__ void detect_kernel(const void* __restrict__ x0raw, int* __restrict__ flag)
{
    const unsigned short* h = (const unsigned short*)x0raw;
    int tid = threadIdx.x;
    int cnt = 0;
    for (int j = tid; j < 8192; j += 256) {
        unsigned short u = h[2 * j];
        int e = (u >> 7) & 0xFF;          // bf16 exponent field
        if (e >= 134) cnt++;              // |v| >= 128: impossible for N(0,1) bf16
    }
    __shared__ int red[256];
    red[tid] = cnt; __syncthreads();
    for (int off = 128; off > 0; off >>= 1) {
        if (tid < off) red[tid] += red[tid + off];
        __syncthreads();
    }
    if (tid == 0) *flag = (red[0] > 400) ? 1 : 0;
}

// ---------------------------------------------------------------------------
__global__ __launch_bounds__(512) void pools_kernel(
    const int* __restrict__ tok, const int* __restrict__ mids,
    const int* __restrict__ mlen, const int* __restrict__ wstart,
    const int* __restrict__ wend, const void* __restrict__ emb,
    float* __restrict__ left, float* __restrict__ right,
    float* __restrict__ glob, float* __restrict__ motif,
    const int* __restrict__ dflag)
{
    const int f32 = *dflag;
    int b = blockIdx.x;
    int d = threadIdx.x;
    int ws_ = wstart[b], we_ = wend[b];
    float sl = 0.f, sr = 0.f, sg = 0.f;
    for (int l = 0; l < cL; ++l) {
        int t = tok[b * cL + l];
        float h = ldx(emb, (size_t)t * cD + d, f32);
        sg += h;
        if (l < ws_) sl += h;
        if (l >= we_) sr += h;
    }
    left[b * cD + d]  = sl / fmaxf((float)ws_, 1.f);
    right[b * cD + d] = sr / fmaxf((float)(cL - we_), 1.f);
    glob[b * cD + d]  = sg / (float)cL;
    int ml = mlen[b];
    float sm = 0.f;
    for (int j = 0; j < cM; ++j) {
        if (j < ml) sm += ldx(emb, (size_t)mids[b * cM + j] * cD + d, f32);
    }
    motif[b * cD + d] = sm / fmaxf((float)ml, 1.f);
}

// ---------------------------------------------------------------------------
__global__ __launch_bounds__(512) void cond_temb_kernel(
    const float* __restrict__ motif, const float* __restrict__ left,
    const float* __restrict__ right, const float* __restrict__ glob,
    const void* __restrict__ t_arr,
    const void* __restrict__ cond_W, const void* __restrict__ cond_b,
    const void* __restrict__ tp_W, const void* __restrict__ tp_b,
    float* __restrict__ cond, float* __restrict__ temb,
    const int* __restrict__ dflag)
{
    const int f32 = *dflag;
    __shared__ float feat[4 * cD];
    __shared__ float tf[cD];
    int b = blockIdx.x;
    int d = threadIdx.x;
    feat[d]          = motif[b * cD + d];
    feat[cD + d]     = left[b * cD + d];
    feat[2 * cD + d] = right[b * cD + d];
    feat[3 * cD + d] = glob[b * cD + d];
    float t = ldx(t_arr, b, f32);
    const int half = cD / 2;
    {
        int j = d;
        if (j < half) {
            float fr = expf(-logf(10000.f) * (float)j / (float)(half - 1));
            tf[j] = sinf(t * fr);
        } else {
            float fr = expf(-logf(10000.f) * (float)(j - half) / (float)(half - 1));
            tf[j] = cosf(t * fr);
        }
    }
    __syncthreads();
    float sc = 0.f;
    for (int k = 0; k < 4 * cD; ++k)
        sc += feat[k] * ldx(cond_W, (size_t)d * (4 * cD) + k, f32);
    cond[b * cD + d] = sc + ldx(cond_b, d, f32);
    float st = 0.f;
    for (int k = 0; k < cD; ++k)
        st += tf[k] * ldx(tp_W, (size_t)d * cD + k, f32);
    temb[b * cD + d] = st + ldx(tp_b, d, f32);
}

// ---------------------------------------------------------------------------
__global__ __launch_bounds__(512) void build_x_kernel(
    const int* __restrict__ tok, const int* __restrict__ wstart,
    const int* __restrict__ wend, const void* __restrict__ t_arr,
    const void* __restrict__ x0, const void* __restrict__ emb,
    const float* __restrict__ cond, const float* __restrict__ temb,
    float* __restrict__ x, float* __restrict__ x1, float* __restrict__ xt,
    const int* __restrict__ dflag)
{
    const int f32 = *dflag;
    int row = blockIdx.x;
    int b = row / cS, s = row % cS;
    int d = threadIdx.x;
    if (s == 0) { x[(size_t)row * cD + d] = cond[b * cD + d]; return; }
    int i = s - 1;
    int ws_ = wstart[b], we_ = wend[b];
    int actual = min(max(we_ - ws_, 0), cWIN);
    int idx = min(ws_ + i, cL - 1);
    float x1v = 0.f;
    if (i < actual) x1v = ldx(emb, (size_t)tok[b * cL + idx] * cD + d, f32);
    float t = ldx(t_arr, b, f32);
    float x0v = ldx(x0, ((size_t)b * cWIN + i) * cD + d, f32);
    float xtv = (1.f - t) * x0v + t * x1v;
    size_t ro = ((size_t)b * cWIN + i) * cD + d;
    x1[ro] = x1v;
    xt[ro] = xtv;
    x[(size_t)row * cD + d] = xtv + temb[b * cD + d];
}

// ---------------------------------------------------------------------------
// GEMM: C[M,N] = A[M,K] @ W[N,K]^T + bias (+relu). W/bias flagged dtype with
// ELEMENT offsets wOff/bOff applied in-kernel (host can't know elem size).
constexpr int TSM = 64, TSN = 64, TSK = 16;
__global__ __launch_bounds__(256) void gemm_nt(
    const float* __restrict__ A, const void* __restrict__ Wb, size_t wOff,
    const void* __restrict__ biasb, size_t bOff, float* __restrict__ C,
    int Mdim, int Ndim, int Kdim, int relu, const int* __restrict__ dflag)
{
    const int f32 = *dflag;
    const void* W = f32 ? (const void*)((const float*)Wb + wOff)
                        : (const void*)((const bf16*)Wb + wOff);
    const void* bias = f32 ? (const void*)((const float*)biasb + bOff)
                           : (const void*)((const bf16*)biasb + bOff);
    __shared__ float As[TSM][TSK + 1];
    __shared__ float Bs[TSN][TSK + 1];
    int tid = threadIdx.x;
    int tx = tid % 16;
    int ty = tid / 16;
    int m0 = blockIdx.y * TSM;
    int n0 = blockIdx.x * TSN;
    float acc[4][4] = {};
    for (int k0 = 0; k0 < Kdim; k0 += TSK) {
        for (int i = tid; i < TSM * TSK; i += 256) {
            int r = i / TSK, c = i % TSK;
            int gm = m0 + r;
            As[r][c] = (gm < Mdim) ? A[(size_t)gm * Kdim + k0 + c] : 0.f;
        }
        for (int i = tid; i < TSN * TSK; i += 256) {
            int r = i / TSK, c = i % TSK;
            int gn = n0 + r;
            Bs[r][c] = (gn < Ndim) ? ldx(W, (size_t)gn * Kdim + k0 + c, f32) : 0.f;
        }
        __syncthreads();
        #pragma unroll
        for (int kk = 0; kk < TSK; ++kk) {
            float a[4], bb[4];
            #pragma unroll
            for (int i = 0; i < 4; ++i) a[i] = As[ty * 4 + i][kk];
            #pragma unroll
            for (int j = 0; j < 4; ++j) bb[j] = Bs[tx * 4 + j][kk];
            #pragma unroll
            for (int i = 0; i < 4; ++i)
                #pragma unroll
                for (int j = 0; j < 4; ++j)
                    acc[i][j] += a[i] * bb[j];
        }
        __syncthreads();
    }
    #pragma unroll
    for (int i = 0; i < 4; ++i) {
        int gm = m0 + ty * 4 + i;
        if (gm >= Mdim) continue;
        #pragma unroll
        for (int j = 0; j < 4; ++j) {
            int gn = n0 + tx * 4 + j;
            if (gn >= Ndim) continue;
            float v = acc[i][j] + ldx(bias, gn, f32);
            if (relu) v = fmaxf(v, 0.f);
            C[(size_t)gm * Ndim + gn] = v;
        }
    }
}

// ---------------------------------------------------------------------------
__global__ __launch_bounds__(128) void attn_kernel(
    const float* __restrict__ qkv, float* __restrict__ ctx)
{
    int s = blockIdx.x, h = blockIdx.y, b = blockIdx.z;
    __shared__ float qv[cHD];
    __shared__ float sc[cS];
    __shared__ float red[128];
    int tid = threadIdx.x;
    const float* base = qkv + (size_t)b * cS * (3 * cD);
    if (tid < cHD) qv[tid] = base[(size_t)s * (3 * cD) + h * cHD + tid];
    __syncthreads();
    for (int k = tid; k < cS; k += 128) {
        const float* kv = base + (size_t)k * (3 * cD) + cD + h * cHD;
        float dot = 0.f;
        #pragma unroll
        for (int e = 0; e < cHD; ++e) dot += qv[e] * kv[e];
        sc[k] = dot * 0.125f;
    }
    __syncthreads();
    float m = -1e30f;
    for (int k = tid; k < cS; k += 128) m = fmaxf(m, sc[k]);
    red[tid] = m; __syncthreads();
    for (int off = 64; off > 0; off >>= 1) {
        if (tid < off) red[tid] = fmaxf(red[tid], red[tid + off]);
        __syncthreads();
    }
    m = red[0];
    __syncthreads();
    float sum = 0.f;
    for (int k = tid; k < cS; k += 128) {
        float e = expf(sc[k] - m);
        sc[k] = e;
        sum += e;
    }
    red[tid] = sum; __syncthreads();
    for (int off = 64; off > 0; off >>= 1) {
        if (tid < off) red[tid] += red[tid + off];
        __syncthreads();
    }
    float inv = 1.f / red[0];
    if (tid < cHD) {
        float acc = 0.f;
        for (int k = 0; k < cS; ++k)
            acc += sc[k] * base[(size_t)k * (3 * cD) + 2 * cD + h * cHD + tid];
        ctx[((size_t)(b * cS + s)) * cD + h * cHD + tid] = acc * inv;
    }
}

// ---------------------------------------------------------------------------
// x = LN(x + h); g/beta flagged dtype with element offset.
__global__ __launch_bounds__(256) void resid_ln_kernel(
    float* __restrict__ x, const float* __restrict__ h,
    const void* __restrict__ g, const void* __restrict__ bta, size_t off,
    const int* __restrict__ dflag)
{
    const int f32 = *dflag;
    int row = blockIdx.x;
    int tid = threadIdx.x;
    __shared__ float red[256];
    float v[2];
    float s = 0.f;
    #pragma unroll
    for (int j = 0; j < 2; ++j) {
        int d = tid + j * 256;
        v[j] = x[(size_t)row * cD + d] + h[(size_t)row * cD + d];
        s += v[j];
    }
    red[tid] = s; __syncthreads();
    for (int o = 128; o > 0; o >>= 1) {
        if (tid < o) red[tid] += red[tid + o];
        __syncthreads();
    }
    float mean = red[0] / (float)cD;
    __syncthreads();
    float vs = 0.f;
    #pragma unroll
    for (int j = 0; j < 2; ++j) { float dd = v[j] - mean; vs += dd * dd; }
    red[tid] = vs; __syncthreads();
    for (int o = 128; o > 0; o >>= 1) {
        if (tid < o) red[tid] += red[tid + o];
        __syncthreads();
    }
    float rs = rsqrtf(red[0] / (float)cD + cEPS);
    #pragma unroll
    for (int j = 0; j < 2; ++j) {
        int d = tid + j * 256;
        x[(size_t)row * cD + d] = (v[j] - mean) * rs * ldx(g, off + d, f32)
                                  + ldx(bta, off + d, f32);
    }
}

// ---------------------------------------------------------------------------
__global__ __launch_bounds__(512) void copy_xs_kernel(
    const float* __restrict__ x, float* __restrict__ xs)
{
    int row = blockIdx.x;
    int b = row / cWIN, i = row % cWIN;
    int d = threadIdx.x;
    xs[(size_t)row * cD + d] = x[((size_t)(b * cS + 1 + i)) * cD + d];
}

// ---------------------------------------------------------------------------
__global__ __launch_bounds__(256) void vel_kernel(
    const float* __restrict__ pv, const float* __restrict__ x1,
    const void* __restrict__ x0, const int* __restrict__ wstart,
    const int* __restrict__ wend, float* __restrict__ velpart,
    const int* __restrict__ dflag)
{
    const int f32 = *dflag;
    int row = blockIdx.x;
    int b = row / cWIN, i = row % cWIN;
    int tid = threadIdx.x;
    int actual = min(max(wend[b] - wstart[b], 0), cWIN);
    if (i >= actual) {
        if (tid == 0) velpart[row] = 0.f;
        return;
    }
    __shared__ float red[256];
    float s = 0.f;
    for (int d = tid; d < cD; d += 256) {
        size_t o = (size_t)row * cD + d;
        float tv = x1[o] - ldx(x0, o, f32);
        float diff = pv[o] - tv;
        s += diff * diff;
    }
    red[tid] = s; __syncthreads();
    for (int off = 128; off > 0; off >>= 1) {
        if (tid < off) red[tid] += red[tid + off];
        __syncthreads();
    }
    if (tid == 0) velpart[row] = red[0];
}

// ---------------------------------------------------------------------------
__global__ __launch_bounds__(512) void predx1_kernel(
    const float* __restrict__ xt, const float* __restrict__ pv,
    const void* __restrict__ t_arr, float* __restrict__ outp,
    const int* __restrict__ dflag)
{
    const int f32 = *dflag;
    int row = blockIdx.x;
    int b = row / cWIN;
    int d = threadIdx.x;
    float t = ldx(t_arr, b, f32);
    size_t o = (size_t)row * cD + d;
    outp[o] = xt[o] + (1.f - t) * pv[o];
}

// ---------------------------------------------------------------------------
__global__ __launch_bounds__(256) void decode_kernel(
    const float* __restrict__ h2, const int* __restrict__ tok,
    const int* __restrict__ wstart, const int* __restrict__ wend,
    const void* __restrict__ dW, const void* __restrict__ db,
    float* __restrict__ logppart, const int* __restrict__ dflag)
{
    const int f32 = *dflag;
    int row = blockIdx.x;
    int b = row / cWIN, i = row % cWIN;
    int tid = threadIdx.x;
    int ws_ = wstart[b], we_ = wend[b];
    int actual = min(max(we_ - ws_, 0), cWIN);
    if (i >= actual) {
        if (tid == 0) logppart[row] = 0.f;
        return;
    }
    int label = tok[b * cL + min(ws_ + i, cL - 1)];
    __shared__ float hrow[cD];
    __shared__ float redm[256], reds[256];
    __shared__ float labellogit;
    for (int d = tid; d < cD; d += 256) hrow[d] = h2[(size_t)row * cD + d];
    __syncthreads();
    float m = -1e30f, ssum = 0.f;
    for (int v = tid; v < cV; v += 256) {
        float dot = 0.f;
        if (f32) {
            const float4* wr4 = reinterpret_cast<const float4*>(
                (const float*)dW + (size_t)v * cD);
            for (int k4 = 0; k4 < cD / 4; ++k4) {
                float4 w4 = wr4[k4];
                int kb = k4 * 4;
                dot += hrow[kb] * w4.x + hrow[kb + 1] * w4.y
                     + hrow[kb + 2] * w4.z + hrow[kb + 3] * w4.w;
            }
            dot += ((const float*)db)[v];
        } else {
            const float4* wr4 = reinterpret_cast<const float4*>(
                (const bf16*)dW + (size_t)v * cD);
            for (int k8 = 0; k8 < cD / 8; ++k8) {
                float4 w4 = wr4[k8];
                const bf16* hw = reinterpret_cast<const bf16*>(&w4);
                int kb = k8 * 8;
                #pragma unroll
                for (int j = 0; j < 8; ++j) dot += hrow[kb + j] * b2f(hw[j]);
            }
            dot += b2f(((const bf16*)db)[v]);
        }
        if (v == label) labellogit = dot;
        if (dot > m) { ssum = ssum * expf(m - dot) + 1.f; m = dot; }
        else ssum += expf(dot - m);
    }
    redm[tid] = m; reds[tid] = ssum; __syncthreads();
    for (int off = 128; off > 0; off >>= 1) {
        if (tid < off) {
            float m2 = redm[tid + off], s2 = reds[tid + off];
            float mm = fmaxf(redm[tid], m2);
            reds[tid] = reds[tid] * expf(redm[tid] - mm) + s2 * expf(m2 - mm);
            redm[tid] = mm;
        }
        __syncthreads();
    }
    if (tid == 0) {
        float logZ = redm[0] + logf(reds[0]);
        logppart[row] = labellogit - logZ;
    }
}

// ---------------------------------------------------------------------------
__global__ __launch_bounds__(256) void finalize_kernel(
    const float* __restrict__ velpart, const float* __restrict__ logppart,
    const int* __restrict__ wstart, const int* __restrict__ wend,
    void* __restrict__ out, const int* __restrict__ dflag)
{
    const int f32 = *dflag;
    __shared__ float r1[256], r2[256];
    int tid = threadIdx.x;
    float s1 = 0.f, s2 = 0.f;
    for (int r = tid; r < cB * cWIN; r += 256) {
        s1 += velpart[r];
        s2 += logppart[r];
    }
    r1[tid] = s1; r2[tid] = s2; __syncthreads();
    for (int off = 128; off > 0; off >>= 1) {
        if (tid < off) { r1[tid] += r1[tid + off]; r2[tid] += r2[tid + off]; }
        __syncthreads();
    }
    if (tid == 0) {
        float cnt = 0.f;
        for (int b = 0; b < cB; ++b)
            cnt += (float)min(max(wend[b] - wstart[b], 0), cWIN);
        cnt = fmaxf(cnt, 1.f);
        float vel = r1[0] / (cnt * (float)cD);
        float recon = -r2[0] / cnt;
        float loss = vel + cRECON_W * recon;
        if (f32) ((float*)out)[0] = loss;
        else     ((bf16*)out)[0] = __float2bfloat16(loss);
    }
}

// ===========================================================================
extern "C" void kernel_launch(void* const* d_in, const int* in_sizes, int n_in,
                              void* d_out, int out_size, void* d_ws, size_t ws_size,
                              hipStream_t stream) {
    const int*  token_ids    = (const int*)d_in[0];
    const int*  motif_ids    = (const int*)d_in[1];
    const int*  motif_len    = (const int*)d_in[2];
    const int*  window_start = (const int*)d_in[3];
    const int*  window_end   = (const int*)d_in[4];
    const void* t_arr        = d_in[5];
    const void* x0           = d_in[6];
    const void* embed_table  = d_in[7];
    const void* decode_W     = d_in[8];
    const void* decode_b     = d_in[9];
    const void* adapter_W    = d_in[10];
    const void* adapter_b    = d_in[11];
    const void* time_proj_W  = d_in[12];
    const void* time_proj_b  = d_in[13];
    const void* cond_proj_W  = d_in[14];
    const void* cond_proj_b  = d_in[15];
    const void* qkv_W        = d_in[16];
    const void* qkv_b        = d_in[17];
    const void* attn_out_W   = d_in[18];
    const void* attn_out_b   = d_in[19];
    const void* ff1_W        = d_in[20];
    const void* ff1_b        = d_in[21];
    const void* ff2_W        = d_in[22];
    const void* ff2_b        = d_in[23];
    const void* ln1_g        = d_in[24];
    const void* ln1_b        = d_in[25];
    const void* ln2_g        = d_in[26];
    const void* ln2_b        = d_in[27];
    const void* out_W        = d_in[28];
    const void* out_b        = d_in[29];

    float* w = (float*)d_ws;
    const size_t SZ_X   = (size_t)cB * cS * cD;
    const size_t SZ_BA  = (size_t)cB * cS * cFF;
    const size_t SZ_ROW = (size_t)cB * cWIN * cD;
    float* x     = w;
    float* bufA  = x + SZ_X;
    float* bufB  = bufA + SZ_BA;
    float* bufC  = bufB + SZ_X;
    float* x1b   = bufC + SZ_X;
    float* xtb   = x1b + SZ_ROW;
    float* pvb   = xtb + SZ_ROW;
    float* h2b   = pvb + SZ_ROW;
    float* motif = h2b + SZ_ROW;
    float* left  = motif + (size_t)cB * cD;
    float* right = left + (size_t)cB * cD;
    float* glob  = right + (size_t)cB * cD;
    float* cond  = glob + (size_t)cB * cD;
    float* temb  = cond + (size_t)cB * cD;
    float* velpart = temb + (size_t)cB * cD;
    float* logppart = velpart + (size_t)cB * cWIN;
    int*   dflag = (int*)(logppart + (size_t)cB * cWIN);

    const int Mrows = cB * cS;
    const int Wrows = cB * cWIN;

    detect_kernel<<<1, 256, 0, stream>>>(x0, dflag);
    pools_kernel<<<cB, cD, 0, stream>>>(token_ids, motif_ids, motif_len,
        window_start, window_end, embed_table, left, right, glob, motif, dflag);
    cond_temb_kernel<<<cB, cD, 0, stream>>>(motif, left, right, glob, t_arr,
        cond_proj_W, cond_proj_b, time_proj_W, time_proj_b, cond, temb, dflag);
    build_x_kernel<<<Mrows, cD, 0, stream>>>(token_ids, window_start, window_end,
        t_arr, x0, embed_table, cond, temb, x, x1b, xtb, dflag);

    auto gemm = [&](const float* A, const void* W, size_t wOff,
                    const void* bias, size_t bOff, float* C,
                    int M_, int N_, int K_, int relu) {
        dim3 grid((N_ + TSN - 1) / TSN, (M_ + TSM - 1) / TSM);
        gemm_nt<<<grid, 256, 0, stream>>>(A, W, wOff, bias, bOff, C,
                                          M_, N_, K_, relu, dflag);
    };

    for (int i = 0; i < cNL; ++i) {
        gemm(x, qkv_W, (size_t)i * 3 * cD * cD, qkv_b, (size_t)i * 3 * cD,
             bufA, Mrows, 3 * cD, cD, 0);
        attn_kernel<<<dim3(cS, cH, cB), 128, 0, stream>>>(bufA, bufB);
        gemm(bufB, attn_out_W, (size_t)i * cD * cD, attn_out_b, (size_t)i * cD,
             bufC, Mrows, cD, cD, 0);
        resid_ln_kernel<<<Mrows, 256, 0, stream>>>(x, bufC, ln1_g, ln1_b,
             (size_t)i * cD, dflag);
        gemm(x, ff1_W, (size_t)i * cFF * cD, ff1_b, (size_t)i * cFF,
             bufA, Mrows, cFF, cD, 1);
        gemm(bufA, ff2_W, (size_t)i * cD * cFF, ff2_b, (size_t)i * cD,
             bufC, Mrows, cD, cFF, 0);
        resid_ln_kernel<<<Mrows, 256, 0, stream>>>(x, bufC, ln2_g, ln2_b,
             (size_t)i * cD, dflag);
    }

    copy_xs_kernel<<<Wrows, cD, 0, stream>>>(x, bufC);
    gemm(bufC, out_W, 0, out_b, 0, pvb, Wrows, cD, cD, 0);
    vel_kernel<<<Wrows, 256, 0, stream>>>(pvb, x1b, x0, window_start, window_end,
        velpart, dflag);
    predx1_kernel<<<Wrows, cD, 0, stream>>>(xtb, pvb, t_arr, bufC, dflag);
    gemm(bufC, adapter_W, 0, adapter_b, 0, h2b, Wrows, cD, cD, 0);
    decode_kernel<<<Wrows, 256, 0, stream>>>(h2b, token_ids, window_start, window_end,
        decode_W, decode_b, logppart, dflag);
    finalize_kernel<<<1, 256, 0, stream>>>(velpart, logppart,
        window_start, window_end, d_out, dflag);
}